// Round 5
// baseline (8269.950 us; speedup 1.0000x reference)
//
#include <hip/hip_runtime.h>
#include <hip/hip_bf16.h>

// ---------- types ----------
typedef __attribute__((ext_vector_type(8))) short  s16x8;
typedef __attribute__((ext_vector_type(4))) float  f32x4;
typedef __attribute__((ext_vector_type(4))) unsigned short u16x4;

#define B_  64
#define T_  1024
#define I_  512
#define H_  1024
#define O_  512
#define MT_ 65536   // B_*T_
#define BH_ 65536   // B_*H_ elements per h step

// scan decomposition: 4 row-groups x 16 col-slices
#define RG_   4
#define CS_   16
#define WSLD  1048   // LDS row stride (shorts)

// ---------- helpers ----------
__device__ __forceinline__ unsigned short f2bf(float f) {
    unsigned u = __builtin_bit_cast(unsigned, f);
    u += 0x7FFFu + ((u >> 16) & 1u);
    return (unsigned short)(u >> 16);
}
__device__ __forceinline__ float bf2f(unsigned short h) {
    return __builtin_bit_cast(float, ((unsigned)h) << 16);
}
__device__ __forceinline__ void store_out(float* p, float v) { *p = v; }
__device__ __forceinline__ void store_out(unsigned short* p, float v) { *p = f2bf(v); }
__device__ __forceinline__ float to_f32(float v) { return v; }
__device__ __forceinline__ float to_f32(unsigned short v) { return bf2f(v); }
__device__ __forceinline__ unsigned umax_(unsigned a, unsigned b) { return a > b ? a : b; }

#define GL2LDS16(gp, lp) __builtin_amdgcn_global_load_lds( \
    (const __attribute__((address_space(1))) void*)(gp),   \
    (__attribute__((address_space(3))) void*)(lp), 16, 0, 0)

// ---------- conversion kernels ----------
__global__ void cvt_x(const float* __restrict__ src, unsigned short* __restrict__ dst, int n) {
    int stride = gridDim.x * blockDim.x * 4;
    for (int i = (blockIdx.x * blockDim.x + threadIdx.x) * 4; i < n; i += stride) {
        const float4 v = *(const float4*)(src + i);
        u16x4 o;
        o.x = f2bf(v.x); o.y = f2bf(v.y); o.z = f2bf(v.z); o.w = f2bf(v.w);
        *(u16x4*)(dst + i) = o;
    }
}

// dst[c][r] = bf16(src[row_off + r][c]);  src region [SR,SC] row-major -> dst [SC,SR]
__global__ void cvt_t(const float* __restrict__ src, unsigned short* __restrict__ dst,
                      int SR, int SC, int row_off) {
    __shared__ unsigned short tile[32][33];
    int c0 = blockIdx.x * 32, r0 = blockIdx.y * 32;
    int tx = threadIdx.x, ty = threadIdx.y;
    #pragma unroll
    for (int i = 0; i < 32; i += 8)
        tile[ty + i][tx] = f2bf(src[(size_t)(row_off + r0 + ty + i) * SC + c0 + tx]);
    __syncthreads();
    #pragma unroll
    for (int i = 0; i < 32; i += 8)
        dst[(size_t)(c0 + ty + i) * SR + r0 + tx] = tile[tx][ty + i];
}

// ---------- init: hist[0] = zeros, hist[1..T] = 0xFFFF sentinel ----------
__global__ void init_hist(uint4* __restrict__ hist) {
    const uint4 z = {0u, 0u, 0u, 0u};
    const uint4 s = {~0u, ~0u, ~0u, ~0u};
    const size_t n16 = (size_t)(T_ + 1) * BH_ / 8;   // 16B chunks
    const size_t z16 = (size_t)BH_ / 8;
    size_t stride = (size_t)gridDim.x * blockDim.x;
    for (size_t i = (size_t)blockIdx.x * blockDim.x + threadIdx.x; i < n16; i += stride)
        hist[i] = (i < z16) ? z : s;
}

// ---------- generic bf16 MFMA GEMM: C[M,N] = act(A[M,K] @ BT[N,K]^T + bias) ----------
template<typename OutT, bool LRELU, bool SCATTER>
__global__ __launch_bounds__(256)
void gemm_bf16(const unsigned short* __restrict__ A,
               const unsigned short* __restrict__ BT,
               const float* __restrict__ bias,
               OutT* __restrict__ C, int M, int K, int N)
{
    __shared__ unsigned short As[4096]; // [128][32]
    __shared__ unsigned short Bs[4096]; // [128][32]
    const int tid = threadIdx.x, lane = tid & 63, wid = tid >> 6;
    const int wr = wid >> 1, wc = wid & 1;
    const int m0 = blockIdx.x * 128, n0 = blockIdx.y * 128;

    f32x4 acc[4][4] = {};

    const int c = wid * 2;
    const int srow = lane >> 2;
    const int scol = (lane & 3) * 8;
    const unsigned short* Ag0 = A  + (size_t)(m0 + c * 16 + srow) * K + scol;
    const unsigned short* Ag1 = A  + (size_t)(m0 + c * 16 + 16 + srow) * K + scol;
    const unsigned short* Bg0 = BT + (size_t)(n0 + c * 16 + srow) * K + scol;
    const unsigned short* Bg1 = BT + (size_t)(n0 + c * 16 + 16 + srow) * K + scol;

    for (int k0 = 0; k0 < K; k0 += 32) {
        __syncthreads();
        GL2LDS16(Ag0 + k0, As + c * 512);
        GL2LDS16(Ag1 + k0, As + (c + 1) * 512);
        GL2LDS16(Bg0 + k0, Bs + c * 512);
        GL2LDS16(Bg1 + k0, Bs + (c + 1) * 512);
        __syncthreads();

        s16x8 af[4], bfr[4];
        #pragma unroll
        for (int i = 0; i < 4; i++)
            af[i] = *(const s16x8*)(As + (wr * 64 + i * 16 + (lane & 15)) * 32 + (lane >> 4) * 8);
        #pragma unroll
        for (int j = 0; j < 4; j++)
            bfr[j] = *(const s16x8*)(Bs + (wc * 64 + j * 16 + (lane & 15)) * 32 + (lane >> 4) * 8);
        #pragma unroll
        for (int i = 0; i < 4; i++)
            #pragma unroll
            for (int j = 0; j < 4; j++)
                acc[i][j] = __builtin_amdgcn_mfma_f32_16x16x32_bf16(af[i], bfr[j], acc[i][j], 0, 0, 0);
    }

    #pragma unroll
    for (int j = 0; j < 4; j++) {
        const int n = n0 + wc * 64 + j * 16 + (lane & 15);
        const float bv = bias[n];
        #pragma unroll
        for (int i = 0; i < 4; i++) {
            #pragma unroll
            for (int r = 0; r < 4; r++) {
                const int m = m0 + wr * 64 + i * 16 + (lane >> 4) * 4 + r;
                if (m < M) {
                    float v = acc[i][j][r] + bv;
                    if (LRELU) v = v >= 0.f ? v : 0.01f * v;
                    size_t row = SCATTER ? (size_t)((m & (T_ - 1)) * B_ + (m >> 10)) : (size_t)m;
                    store_out(&C[row * N + n], v);
                }
            }
        }
    }
}

// ---------- scan v5: sentinel data-poll, write-once h history ----------
// 64 blocks (4 rg x 16 cs) x 256 thr. No flags, no store-ack waits. hist[t] is
// write-once: producer fires one 8B sc0sc1 store and proceeds. Consumer polls
// the data: burst-load 32 chunks (sc0 sc1), validate each u32 != 0xFFFFFFFF
// (0xFFFF is a bf16 NaN pattern f2bf never produces; hist pre-poisoned).

#define HL(d, OFFSTR) asm volatile( \
    "global_load_dwordx4 %0, %1, off offset:" OFFSTR " sc0 sc1" \
    : "=v"(d) : "v"(hbase))

#define WAITV0 do { \
    asm volatile("s_waitcnt vmcnt(0)" ::: "memory"); \
    __builtin_amdgcn_sched_barrier(0); } while (0)

template<typename PreT>
__global__ __launch_bounds__(256, 1)
void rnn_scan5(const unsigned short* __restrict__ WbotT,
               const PreT* __restrict__ pre,       // [T][B][H] t-major
               unsigned short* __restrict__ hist)  // [T+1][B][H] bf16
{
    __shared__ unsigned short Ws[64 * WSLD];
    const int tid = threadIdx.x, lane = tid & 63, w = tid >> 6;
    const int rg = (int)blockIdx.x >> 4;
    const int cs = (int)blockIdx.x & 15;
    const int row0 = rg * 16, n0 = cs * 64;

    for (int idx = tid; idx < 64 * 128; idx += 256) {
        int r = idx >> 7, ck = (idx & 127) * 8;
        *(s16x8*)(Ws + r * WSLD + ck) = *(const s16x8*)(WbotT + (size_t)(n0 + r) * H_ + ck);
    }
    __syncthreads();

    const int l15 = lane & 15, l4 = lane >> 4;
    const int hrow = row0 + l15;              // h row this thread reads AND writes
    const int col0 = n0 + w * 16 + l4 * 4;    // 4 consecutive output cols
    const unsigned short* wsbase = Ws + (size_t)(w * 16 + l15) * WSLD + l4 * 8;

    float pv[4];
    #pragma unroll
    for (int r = 0; r < 4; r++)
        pv[r] = to_f32(pre[(size_t)hrow * H_ + col0 + r]);

    for (int t = 0; t < T_; ++t) {
        const unsigned short* hc = hist + (size_t)t * BH_;
        unsigned short*       hn = hist + (size_t)(t + 1) * BH_;

        // next-step pre prefetch (plain cached; drained by first poll round)
        float pvn[4];
        const int tn = (t + 1 < T_) ? t + 1 : t;
        #pragma unroll
        for (int r = 0; r < 4; r++)
            pvn[r] = to_f32(pre[((size_t)tn * B_ + hrow) * H_ + col0 + r]);

        // data-poll: burst-load the 16-row stripe, retry until all u32 fresh
        const unsigned short* hbase = hc + (size_t)hrow * H_ + l4 * 8;
        s16x8 hv[32];
        for (;;) {
            HL(hv[0],  "0");    HL(hv[1],  "64");   HL(hv[2],  "128");  HL(hv[3],  "192");
            HL(hv[4],  "256");  HL(hv[5],  "320");  HL(hv[6],  "384");  HL(hv[7],  "448");
            HL(hv[8],  "512");  HL(hv[9],  "576");  HL(hv[10], "640");  HL(hv[11], "704");
            HL(hv[12], "768");  HL(hv[13], "832");  HL(hv[14], "896");  HL(hv[15], "960");
            HL(hv[16], "1024"); HL(hv[17], "1088"); HL(hv[18], "1152"); HL(hv[19], "1216");
            HL(hv[20], "1280"); HL(hv[21], "1344"); HL(hv[22], "1408"); HL(hv[23], "1472");
            HL(hv[24], "1536"); HL(hv[25], "1600"); HL(hv[26], "1664"); HL(hv[27], "1728");
            HL(hv[28], "1792"); HL(hv[29], "1856"); HL(hv[30], "1920"); HL(hv[31], "1984");
            WAITV0;
            unsigned m = 0;
            #pragma unroll
            for (int i = 0; i < 32; i++) {
                uint4 wv = __builtin_bit_cast(uint4, hv[i]);
                m = umax_(m, umax_(umax_(wv.x, wv.y), umax_(wv.z, wv.w)));
            }
            if (__all((int)(m != 0xFFFFFFFFu))) break;
        }

        // mfma(Ws_frag, h_frag): thread ends with 4 consecutive cols of one row
        f32x4 ac[4] = {};
        #pragma unroll
        for (int i = 0; i < 32; i++) {
            s16x8 g = *(const s16x8*)(wsbase + i * 32);
            ac[i & 3] = __builtin_amdgcn_mfma_f32_16x16x32_bf16(g, hv[i], ac[i & 3], 0, 0, 0);
        }
        f32x4 acc = (ac[0] + ac[1]) + (ac[2] + ac[3]);

        u16x4 o;
        #pragma unroll
        for (int r = 0; r < 4; r++) {
            float v = acc[r] + pv[r];
            v = v >= 0.f ? v : 0.01f * v;
            o[r] = f2bf(v);
        }
        {
            unsigned long long ov = __builtin_bit_cast(unsigned long long, o);
            unsigned short* sp = hn + (size_t)hrow * H_ + col0;
            asm volatile("global_store_dwordx2 %0, %1, off sc0 sc1"
                         :: "v"(sp), "v"(ov) : "memory");
        }
        // no store-ack wait, no flag: fire and proceed

        #pragma unroll
        for (int r = 0; r < 4; r++) pv[r] = pvn[r];
    }
}

// ---------- launch ----------
extern "C" void kernel_launch(void* const* d_in, const int* in_sizes, int n_in,
                              void* d_out, int out_size, void* d_ws, size_t ws_size,
                              hipStream_t stream)
{
    const float* x     = (const float*)d_in[0];
    const float* W_in  = (const float*)d_in[1];
    const float* b_in  = (const float*)d_in[2];
    const float* W_h   = (const float*)d_in[3];
    const float* b_h   = (const float*)d_in[4];
    const float* W_out = (const float*)d_in[5];
    const float* b_out = (const float*)d_in[6];
    float* out = (float*)d_out;

    char* ws = (char*)d_ws;
    size_t off = 0;
    auto alloc = [&](size_t bytes) { void* p = ws + off; off += (bytes + 255) & ~(size_t)255; return p; };

    unsigned short* Xb    = (unsigned short*)alloc((size_t)MT_ * I_ * 2);
    unsigned short* WinT  = (unsigned short*)alloc((size_t)H_ * I_ * 2);
    unsigned short* WtopT = (unsigned short*)alloc((size_t)H_ * H_ * 2);
    unsigned short* WbotT = (unsigned short*)alloc((size_t)H_ * H_ * 2);
    unsigned short* WoutT = (unsigned short*)alloc((size_t)O_ * H_ * 2);
    // hist [T+1][B][H] bf16; also serves as Abuf (GEMM1 out / GEMM2 in) — disjoint lifetimes
    unsigned short* hist  = (unsigned short*)alloc((size_t)(T_ + 1) * BH_ * 2);
    unsigned short* Abuf  = hist;
    void* pre = ws + off;
    const bool pre_f32 = (off + (size_t)MT_ * H_ * 4) <= ws_size;

    cvt_x<<<2048, 256, 0, stream>>>(x, Xb, MT_ * I_);
    dim3 tb(32, 8);
    cvt_t<<<dim3(H_ / 32, I_ / 32), tb, 0, stream>>>(W_in,  WinT,  I_, H_, 0);
    cvt_t<<<dim3(H_ / 32, H_ / 32), tb, 0, stream>>>(W_h,   WtopT, H_, H_, 0);
    cvt_t<<<dim3(H_ / 32, H_ / 32), tb, 0, stream>>>(W_h,   WbotT, H_, H_, H_);
    cvt_t<<<dim3(O_ / 32, H_ / 32), tb, 0, stream>>>(W_out, WoutT, H_, O_, 0);

    // GEMM1: A = lrelu(X @ W_in + b_in)   [MT, H] bf16
    gemm_bf16<unsigned short, true, false>
        <<<dim3(MT_ / 128, H_ / 128), 256, 0, stream>>>(Xb, WinT, b_in, Abuf, MT_, I_, H_);

    // GEMM2: pre = A @ Wtop + b_h   written t-major [T][B][H]
    if (pre_f32) {
        gemm_bf16<float, false, true>
            <<<dim3(MT_ / 128, H_ / 128), 256, 0, stream>>>(Abuf, WtopT, b_h, (float*)pre, MT_, H_, H_);
        init_hist<<<2048, 256, 0, stream>>>((uint4*)hist);
        rnn_scan5<float><<<RG_ * CS_, 256, 0, stream>>>(WbotT, (const float*)pre, hist);
    } else {
        gemm_bf16<unsigned short, false, true>
            <<<dim3(MT_ / 128, H_ / 128), 256, 0, stream>>>(Abuf, WtopT, b_h, (unsigned short*)pre, MT_, H_, H_);
        init_hist<<<2048, 256, 0, stream>>>((uint4*)hist);
        rnn_scan5<unsigned short><<<RG_ * CS_, 256, 0, stream>>>(WbotT, (const unsigned short*)pre, hist);
    }

    // final: out = h_final @ W_out + b_out   (h_final = hist[T])
    gemm_bf16<float, false, false>
        <<<dim3(1, O_ / 128), 256, 0, stream>>>(hist + (size_t)T_ * BH_, WoutT, b_out, out, B_, H_, O_);
}